// Round 11
// baseline (128.760 us; speedup 1.0000x reference)
//
#include <hip/hip_runtime.h>
#include <hip/hip_bf16.h>

#define NPOS 4096
#define CDIM 64
#define BATCH 2
#define JSPLIT 32                 // j-range split; Opart = 33.5 MB bf16
#define JCHUNK (NPOS / JSPLIT)    // 128 j per block
#define RPB 128                   // q-rows per block (4 waves x 32)
#define PSTR 72                   // P LDS row stride (shorts): 144B, 16B-aligned

typedef __attribute__((ext_vector_type(8))) short bf16x8;
typedef __attribute__((ext_vector_type(4))) float f32x4;
typedef __attribute__((ext_vector_type(4))) unsigned int u32x4;
typedef __attribute__((ext_vector_type(2))) unsigned int u32x2;

static __device__ __forceinline__ unsigned int fbits(float f) {
    union { float f; unsigned int u; } v; v.f = f; return v.u;
}
static __device__ __forceinline__ float bffloat(unsigned int hi16) {
    union { unsigned int u; float f; } v; v.u = hi16; return v.f;
}
static __device__ __forceinline__ unsigned int pk2bf(float a, float b) {
    return ((fbits(a) + 0x8000u) >> 16) | ((fbits(b) + 0x8000u) & 0xffff0000u);
}
static __device__ __forceinline__ short f2bs(float f) {
    return (short)(unsigned short)((fbits(f) + 0x8000u) >> 16);
}

// ---------------------------------------------------------------------------
// Kernel 1: qkv with weff fused IN-REGISTER (verified correct in R10's first
// launch). 1536 one-wave blocks (R7-verified structure). No LDS, no barriers.
// MFMA 16x16x32 bf16 layouts (HW-verified R3-R8):
//   A[m=lane&15][k=quad*8+j]  B[k=quad*8+j][n=lane&15]  C/D[quad*4+r][lane&15]
// x fragment dual-role: B-operand for q/k, A-operand for v.
// ---------------------------------------------------------------------------
__global__ __launch_bounds__(64) void qkv_kernel(
    const float* __restrict__ x,
    const float* __restrict__ q_dw, const float* __restrict__ q_pw,
    const float* __restrict__ k_dw, const float* __restrict__ k_pw,
    const float* __restrict__ v_dw, const float* __restrict__ v_pw,
    short* __restrict__ qT, short* __restrict__ kT, short* __restrict__ vM)
{
    const int bid  = blockIdx.x;
    const int p    = bid >> 9;          // 0=q 1=k 2=v
    const int np   = bid & 511;
    const int b    = np >> 8;
    const int n0   = (np & 255) << 4;
    const int lane = threadIdx.x;
    const int col  = lane & 15;
    const int quad = lane >> 4;
    const int n    = n0 + col;

    const float* pw = (p == 0) ? q_pw : (p == 1) ? k_pw : v_pw;
    const float* dw = (p == 0) ? q_dw : (p == 1) ? k_dw : v_dw;

    bf16x8 xf0, xf1;
    float dv0[8], dv1[8];
    #pragma unroll
    for (int j = 0; j < 8; ++j) {
        xf0[j] = f2bs(x[(size_t)(b * CDIM + quad * 8 + j) * NPOS + n]);
        xf1[j] = f2bs(x[(size_t)(b * CDIM + 32 + quad * 8 + j) * NPOS + n]);
        dv0[j] = dw[quad * 8 + j];
        dv1[j] = dw[32 + quad * 8 + j];
    }

    #pragma unroll
    for (int os = 0; os < 4; ++os) {
        const float* pr = pw + (os * 16 + col) * 64 + quad * 8;
        bf16x8 wf0, wf1;
        #pragma unroll
        for (int j = 0; j < 8; ++j) {
            wf0[j] = f2bs(pr[j] * dv0[j]);
            wf1[j] = f2bs(pr[32 + j] * dv1[j]);
        }
        f32x4 d = (f32x4){0.f, 0.f, 0.f, 0.f};
        if (p < 2) {
            d = __builtin_amdgcn_mfma_f32_16x16x32_bf16(wf0, xf0, d, 0, 0, 0);
            d = __builtin_amdgcn_mfma_f32_16x16x32_bf16(wf1, xf1, d, 0, 0, 0);
            short* dst = p ? kT : qT;
            *(u32x2*)(dst + (size_t)(b * NPOS + n) * CDIM + os * 16 + quad * 4) =
                (u32x2){pk2bf(d[0], d[1]), pk2bf(d[2], d[3])};
        } else {
            d = __builtin_amdgcn_mfma_f32_16x16x32_bf16(xf0, wf0, d, 0, 0, 0);
            d = __builtin_amdgcn_mfma_f32_16x16x32_bf16(xf1, wf1, d, 0, 0, 0);
            *(u32x2*)(vM + (size_t)(b * CDIM + os * 16 + col) * NPOS + n0 + quad * 4) =
                (u32x2){pk2bf(d[0], d[1]), pk2bf(d[2], d[3])};
        }
    }
}

// ---------------------------------------------------------------------------
// Kernel 2: flash attention, JSPLIT=32 (occupancy experiment: R4 counters
// showed latency-bound — VALUBusy 9%, Occupancy 17% at 2 blocks/CU; grid
// 2048 = 8 blocks/CU resident-capable doubles latency hiding). Body is
// R8's verified barrier-free code; only the gid decode and tile count
// changed. Partials: Opart[jc][b][c][n] bf16 + lacc fp32.
// ---------------------------------------------------------------------------
__global__ __launch_bounds__(256, 4) void attn_kernel(
    const short* __restrict__ qT, const short* __restrict__ kT,
    const short* __restrict__ vM,
    unsigned short* __restrict__ Opart, float* __restrict__ lacc)
{
    const int gid  = blockIdx.x;
    const int jc   = gid & (JSPLIT - 1);
    const int rb   = (gid >> 5) & 31;
    const int b    = gid >> 10;
    const int t    = threadIdx.x;
    const int wave = t >> 6;
    const int lane = t & 63;
    const int col  = lane & 15;
    const int quad = lane >> 4;

    __shared__ __align__(16) short Pw[4][32 * PSTR];

    const short* qTb = qT + (size_t)b * NPOS * CDIM;
    const short* kTb = kT + (size_t)b * NPOS * CDIM;
    const short* vb  = vM + (size_t)b * CDIM * NPOS;

    const int i0 = rb * RPB + wave * 32;

    bf16x8 qf[2][2];
    #pragma unroll
    for (int rs = 0; rs < 2; ++rs) {
        const short* qp = qTb + (size_t)(i0 + rs * 16 + col) * CDIM + quad * 8;
        qf[rs][0] = *(const bf16x8*)qp;
        qf[rs][1] = *(const bf16x8*)(qp + 32);
    }

    f32x4 oacc[2][4];
    #pragma unroll
    for (int rs = 0; rs < 2; ++rs)
        #pragma unroll
        for (int cb = 0; cb < 4; ++cb) oacc[rs][cb] = (f32x4){0.f, 0.f, 0.f, 0.f};
    float lp[2] = {0.f, 0.f};

    short* Pme = Pw[wave];

    for (int jt = 0; jt < JCHUNK / 64; ++jt) {
        const int j0 = jc * JCHUNK + jt * 64;

        #pragma unroll
        for (int ct = 0; ct < 4; ++ct) {
            const short* kp = kTb + (size_t)(j0 + ct * 16 + col) * CDIM + quad * 8;
            bf16x8 kf0 = *(const bf16x8*)kp;
            bf16x8 kf1 = *(const bf16x8*)(kp + 32);
            #pragma unroll
            for (int rs = 0; rs < 2; ++rs) {
                f32x4 a = (f32x4){0.f, 0.f, 0.f, 0.f};
                a = __builtin_amdgcn_mfma_f32_16x16x32_bf16(kf0, qf[rs][0], a, 0, 0, 0);
                a = __builtin_amdgcn_mfma_f32_16x16x32_bf16(kf1, qf[rs][1], a, 0, 0, 0);
                float p0 = __expf(a[0]), p1 = __expf(a[1]);
                float p2 = __expf(a[2]), p3 = __expf(a[3]);
                lp[rs] += (p0 + p1) + (p2 + p3);
                *(u32x2*)(Pme + (rs * 16 + col) * PSTR + ct * 16 + quad * 4) =
                    (u32x2){pk2bf(p0, p1), pk2bf(p2, p3)};
            }
        }
        asm volatile("" ::: "memory");   // IR order; DS in-order per wave

        bf16x8 pf[2][2];
        #pragma unroll
        for (int rs = 0; rs < 2; ++rs) {
            const short* pp = Pme + (rs * 16 + col) * PSTR + quad * 8;
            pf[rs][0] = *(const bf16x8*)pp;
            pf[rs][1] = *(const bf16x8*)(pp + 32);
        }
        asm volatile("" ::: "memory");

        #pragma unroll
        for (int cb = 0; cb < 4; ++cb) {
            const short* vp = vb + (size_t)(cb * 16 + col) * NPOS + j0 + quad * 8;
            bf16x8 vf0 = *(const bf16x8*)vp;
            bf16x8 vf1 = *(const bf16x8*)(vp + 32);
            #pragma unroll
            for (int rs = 0; rs < 2; ++rs) {
                oacc[rs][cb] = __builtin_amdgcn_mfma_f32_16x16x32_bf16(vf0, pf[rs][0], oacc[rs][cb], 0, 0, 0);
                oacc[rs][cb] = __builtin_amdgcn_mfma_f32_16x16x32_bf16(vf1, pf[rs][1], oacc[rs][cb], 0, 0, 0);
            }
        }
    }

    #pragma unroll
    for (int rs = 0; rs < 2; ++rs) {
        lp[rs] += __shfl_xor(lp[rs], 16, 64);
        lp[rs] += __shfl_xor(lp[rs], 32, 64);
    }
    if (quad == 0) {
        #pragma unroll
        for (int rs = 0; rs < 2; ++rs)
            lacc[(size_t)(jc * BATCH + b) * NPOS + i0 + rs * 16 + col] = lp[rs];
    }

    unsigned short* Ob = Opart + (size_t)(jc * BATCH + b) * CDIM * NPOS;
    #pragma unroll
    for (int rs = 0; rs < 2; ++rs)
        #pragma unroll
        for (int cb = 0; cb < 4; ++cb)
            #pragma unroll
            for (int r = 0; r < 4; ++r)
                Ob[(size_t)(cb * 16 + quad * 4 + r) * NPOS + i0 + rs * 16 + col] =
                    (unsigned short)f2bs(oacc[rs][cb][r]);
}

// ---------------------------------------------------------------------------
// Kernel 3: out = gamma/lsum * sum_jc Opart + x  (R8 body; 32 partials now)
// ---------------------------------------------------------------------------
__global__ __launch_bounds__(256) void combine_kernel(
    const unsigned short* __restrict__ Opart, const float* __restrict__ lacc,
    const float* __restrict__ x, const float* __restrict__ gamma,
    float* __restrict__ out)
{
    int b  = blockIdx.x >> 7;
    int n0 = (blockIdx.x & 127) << 5;
    __shared__ float linv[32];
    int t = threadIdx.x;
    if (t < 32) {
        float s = 0.f;
        #pragma unroll
        for (int jc = 0; jc < JSPLIT; ++jc)
            s += lacc[(size_t)(jc * BATCH + b) * NPOS + n0 + t];
        linv[t] = gamma[0] / s;
    }
    __syncthreads();

    int c = t >> 2, ns = (t & 3) * 8;
    float acc[8];
    #pragma unroll
    for (int k = 0; k < 8; ++k) acc[k] = 0.f;
    #pragma unroll
    for (int jc = 0; jc < JSPLIT; ++jc) {
        const unsigned short* Ob = Opart + ((size_t)(jc * BATCH + b) * CDIM + c) * NPOS + n0 + ns;
        u32x4 w = *(const u32x4*)Ob;
        #pragma unroll
        for (int j = 0; j < 4; ++j) {
            acc[2 * j]     += bffloat(w[j] << 16);
            acc[2 * j + 1] += bffloat(w[j] & 0xffff0000u);
        }
    }
    const float* xb = x + ((size_t)b * CDIM + c) * NPOS + n0 + ns;
    float* ob = out + ((size_t)b * CDIM + c) * NPOS + n0 + ns;
    #pragma unroll
    for (int k = 0; k < 2; ++k) {
        f32x4 x4 = *(const f32x4*)(xb + k * 4);
        f32x4 r;
        #pragma unroll
        for (int j = 0; j < 4; ++j)
            r[j] = fmaf(acc[k * 4 + j], linv[ns + k * 4 + j], x4[j]);
        *(f32x4*)(ob + k * 4) = r;
    }
}

extern "C" void kernel_launch(void* const* d_in, const int* in_sizes, int n_in,
                              void* d_out, int out_size, void* d_ws, size_t ws_size,
                              hipStream_t stream) {
    const float* x     = (const float*)d_in[0];
    const float* q_dw  = (const float*)d_in[1];
    const float* q_pw  = (const float*)d_in[2];
    const float* k_dw  = (const float*)d_in[3];
    const float* k_pw  = (const float*)d_in[4];
    const float* v_dw  = (const float*)d_in[5];
    const float* v_pw  = (const float*)d_in[6];
    const float* gamma = (const float*)d_in[7];
    float* out = (float*)d_out;

    // ws: qT 1M | kT 1M | vM 1M | Opart 33.5M | lacc 1M
    char* ws = (char*)d_ws;
    short* qT             = (short*)(ws);
    short* kT             = (short*)(ws + (1u << 20));
    short* vM             = (short*)(ws + (2u << 20));
    unsigned short* Opart = (unsigned short*)(ws + (3u << 20));
    float* lacc           = (float*)(ws + (3u << 20) +
                                     (size_t)JSPLIT * BATCH * CDIM * NPOS * 2);

    qkv_kernel<<<3 * BATCH * 256, 64, 0, stream>>>(
        x, q_dw, q_pw, k_dw, k_pw, v_dw, v_pw, qT, kT, vM);
    attn_kernel<<<BATCH * 32 * JSPLIT, 256, 0, stream>>>(qT, kT, vM, Opart, lacc);
    combine_kernel<<<BATCH * 128, 256, 0, stream>>>(Opart, lacc, x, gamma, out);
}

// Round 12
// 118.068 us; speedup vs baseline: 1.0906x; 1.0906x over previous
//
#include <hip/hip_runtime.h>
#include <hip/hip_bf16.h>

#define NPOS 4096
#define CDIM 64
#define BATCH 2
#define JSPLIT 16                 // j-range split; Opart = 16.8 MB bf16
#define JCHUNK (NPOS / JSPLIT)    // 256 j per block (4 tiles of 64)
#define RPB 128                   // q-rows per block (4 waves x 32)
#define PSTR 72                   // P LDS row stride (shorts): 144B, 16B-aligned

typedef __attribute__((ext_vector_type(8))) short bf16x8;
typedef __attribute__((ext_vector_type(4))) short short4b;
typedef __attribute__((ext_vector_type(4))) float f32x4;
typedef __attribute__((ext_vector_type(4))) unsigned int u32x4;
typedef __attribute__((ext_vector_type(2))) unsigned int u32x2;

static __device__ __forceinline__ unsigned int fbits(float f) {
    union { float f; unsigned int u; } v; v.f = f; return v.u;
}
static __device__ __forceinline__ float bffloat(unsigned int hi16) {
    union { unsigned int u; float f; } v; v.u = hi16; return v.f;
}
static __device__ __forceinline__ unsigned int pk2bf(float a, float b) {
    return ((fbits(a) + 0x8000u) >> 16) | ((fbits(b) + 0x8000u) & 0xffff0000u);
}
static __device__ __forceinline__ short f2bs(float f) {
    return (short)(unsigned short)((fbits(f) + 0x8000u) >> 16);
}

// ---------------------------------------------------------------------------
// Kernel 1: qkv with weff fused in-register (R10-first-launch + R11 verified).
// 1536 one-wave blocks. MFMA 16x16x32 bf16 layouts (HW-verified R3-R11):
//   A[m=lane&15][k=quad*8+j]  B[k=quad*8+j][n=lane&15]  C/D[quad*4+r][lane&15]
// ---------------------------------------------------------------------------
__global__ __launch_bounds__(64) void qkv_kernel(
    const float* __restrict__ x,
    const float* __restrict__ q_dw, const float* __restrict__ q_pw,
    const float* __restrict__ k_dw, const float* __restrict__ k_pw,
    const float* __restrict__ v_dw, const float* __restrict__ v_pw,
    short* __restrict__ qT, short* __restrict__ kT, short* __restrict__ vM)
{
    const int bid  = blockIdx.x;
    const int p    = bid >> 9;          // 0=q 1=k 2=v
    const int np   = bid & 511;
    const int b    = np >> 8;
    const int n0   = (np & 255) << 4;
    const int lane = threadIdx.x;
    const int col  = lane & 15;
    const int quad = lane >> 4;
    const int n    = n0 + col;

    const float* pw = (p == 0) ? q_pw : (p == 1) ? k_pw : v_pw;
    const float* dw = (p == 0) ? q_dw : (p == 1) ? k_dw : v_dw;

    bf16x8 xf0, xf1;
    float dv0[8], dv1[8];
    #pragma unroll
    for (int j = 0; j < 8; ++j) {
        xf0[j] = f2bs(x[(size_t)(b * CDIM + quad * 8 + j) * NPOS + n]);
        xf1[j] = f2bs(x[(size_t)(b * CDIM + 32 + quad * 8 + j) * NPOS + n]);
        dv0[j] = dw[quad * 8 + j];
        dv1[j] = dw[32 + quad * 8 + j];
    }

    #pragma unroll
    for (int os = 0; os < 4; ++os) {
        const float* pr = pw + (os * 16 + col) * 64 + quad * 8;
        bf16x8 wf0, wf1;
        #pragma unroll
        for (int j = 0; j < 8; ++j) {
            wf0[j] = f2bs(pr[j] * dv0[j]);
            wf1[j] = f2bs(pr[32 + j] * dv1[j]);
        }
        f32x4 d = (f32x4){0.f, 0.f, 0.f, 0.f};
        if (p < 2) {
            d = __builtin_amdgcn_mfma_f32_16x16x32_bf16(wf0, xf0, d, 0, 0, 0);
            d = __builtin_amdgcn_mfma_f32_16x16x32_bf16(wf1, xf1, d, 0, 0, 0);
            short* dst = p ? kT : qT;
            *(u32x2*)(dst + (size_t)(b * NPOS + n) * CDIM + os * 16 + quad * 4) =
                (u32x2){pk2bf(d[0], d[1]), pk2bf(d[2], d[3])};
        } else {
            d = __builtin_amdgcn_mfma_f32_16x16x32_bf16(xf0, wf0, d, 0, 0, 0);
            d = __builtin_amdgcn_mfma_f32_16x16x32_bf16(xf1, wf1, d, 0, 0, 0);
            *(u32x2*)(vM + (size_t)(b * CDIM + os * 16 + col) * NPOS + n0 + quad * 4) =
                (u32x2){pk2bf(d[0], d[1]), pk2bf(d[2], d[3])};
        }
    }
}

// ---------------------------------------------------------------------------
// Kernel 2: flash attention v3 — chain-shortened. R11 counters proved the
// kernel is NOT TLP-starved (2x occupancy, flat time; 75% of cycles
// stall-bound): each tile serially ate K-load-latency then V-load-latency
// at cross-XCD LLC cost, with asm memory clobbers pinning that order.
// Fix: K AND V fragments load together at tile top (V never depended on P);
// unrolled 4-tile loop lets the scheduler pipeline next-tile loads under
// MFMA/exp; P round-trip ordering via same-elem-type vectors (short4 write,
// short8 read) instead of clobbers. __launch_bounds__(256,3): ~168 VGPR
// budget fits K+V+Q+O live without spills.
// ---------------------------------------------------------------------------
__global__ __launch_bounds__(256, 3) void attn_kernel(
    const short* __restrict__ qT, const short* __restrict__ kT,
    const short* __restrict__ vM,
    unsigned short* __restrict__ Opart, float* __restrict__ lacc)
{
    const int gid  = blockIdx.x;
    const int jc   = gid & (JSPLIT - 1);
    const int rb   = (gid >> 4) & 31;
    const int b    = gid >> 9;
    const int t    = threadIdx.x;
    const int wave = t >> 6;
    const int lane = t & 63;
    const int col  = lane & 15;
    const int quad = lane >> 4;

    __shared__ __align__(16) short Pw[4][32 * PSTR];

    const short* qTb = qT + (size_t)b * NPOS * CDIM;
    const short* kTb = kT + (size_t)b * NPOS * CDIM;
    const short* vb  = vM + (size_t)b * CDIM * NPOS;

    const int i0 = rb * RPB + wave * 32;

    bf16x8 qf[2][2];
    #pragma unroll
    for (int rs = 0; rs < 2; ++rs) {
        const short* qp = qTb + (size_t)(i0 + rs * 16 + col) * CDIM + quad * 8;
        qf[rs][0] = *(const bf16x8*)qp;
        qf[rs][1] = *(const bf16x8*)(qp + 32);
    }

    f32x4 oacc[2][4];
    #pragma unroll
    for (int rs = 0; rs < 2; ++rs)
        #pragma unroll
        for (int cb = 0; cb < 4; ++cb) oacc[rs][cb] = (f32x4){0.f, 0.f, 0.f, 0.f};
    float lp[2] = {0.f, 0.f};

    short* Pme = Pw[wave];

    #pragma unroll
    for (int jt = 0; jt < JCHUNK / 64; ++jt) {
        const int j0 = jc * JCHUNK + jt * 64;

        // ---- ALL global loads for this tile issue together (K and V) ----
        bf16x8 kf[4][2], vf[4][2];
        #pragma unroll
        for (int ct = 0; ct < 4; ++ct) {
            const short* kp = kTb + (size_t)(j0 + ct * 16 + col) * CDIM + quad * 8;
            kf[ct][0] = *(const bf16x8*)kp;
            kf[ct][1] = *(const bf16x8*)(kp + 32);
        }
        #pragma unroll
        for (int cb = 0; cb < 4; ++cb) {
            const short* vp = vb + (size_t)(cb * 16 + col) * NPOS + j0 + quad * 8;
            vf[cb][0] = *(const bf16x8*)vp;
            vf[cb][1] = *(const bf16x8*)(vp + 32);
        }

        // ---- S^T = K.Q^T, exp, pack, stash (short4 b64 DS writes) ----
        #pragma unroll
        for (int ct = 0; ct < 4; ++ct) {
            #pragma unroll
            for (int rs = 0; rs < 2; ++rs) {
                f32x4 a = (f32x4){0.f, 0.f, 0.f, 0.f};
                a = __builtin_amdgcn_mfma_f32_16x16x32_bf16(kf[ct][0], qf[rs][0], a, 0, 0, 0);
                a = __builtin_amdgcn_mfma_f32_16x16x32_bf16(kf[ct][1], qf[rs][1], a, 0, 0, 0);
                float p0 = __expf(a[0]), p1 = __expf(a[1]);
                float p2 = __expf(a[2]), p3 = __expf(a[3]);
                lp[rs] += (p0 + p1) + (p2 + p3);
                *(short4b*)(Pme + (rs * 16 + col) * PSTR + ct * 16 + quad * 4) =
                    (short4b){f2bs(p0), f2bs(p1), f2bs(p2), f2bs(p3)};
            }
        }

        // ---- P fragments back (same-wave DS, same-elem-type aliasing) ----
        bf16x8 pf[2][2];
        #pragma unroll
        for (int rs = 0; rs < 2; ++rs) {
            const short* pp = Pme + (rs * 16 + col) * PSTR + quad * 8;
            pf[rs][0] = *(const bf16x8*)pp;
            pf[rs][1] = *(const bf16x8*)(pp + 32);
        }

        // ---- O^T += V^T . P^T (V already resident) ----
        #pragma unroll
        for (int cb = 0; cb < 4; ++cb)
            #pragma unroll
            for (int rs = 0; rs < 2; ++rs) {
                oacc[rs][cb] = __builtin_amdgcn_mfma_f32_16x16x32_bf16(vf[cb][0], pf[rs][0], oacc[rs][cb], 0, 0, 0);
                oacc[rs][cb] = __builtin_amdgcn_mfma_f32_16x16x32_bf16(vf[cb][1], pf[rs][1], oacc[rs][cb], 0, 0, 0);
            }
    }

    #pragma unroll
    for (int rs = 0; rs < 2; ++rs) {
        lp[rs] += __shfl_xor(lp[rs], 16, 64);
        lp[rs] += __shfl_xor(lp[rs], 32, 64);
    }
    if (quad == 0) {
        #pragma unroll
        for (int rs = 0; rs < 2; ++rs)
            lacc[(size_t)(jc * BATCH + b) * NPOS + i0 + rs * 16 + col] = lp[rs];
    }

    unsigned short* Ob = Opart + (size_t)(jc * BATCH + b) * CDIM * NPOS;
    #pragma unroll
    for (int rs = 0; rs < 2; ++rs)
        #pragma unroll
        for (int cb = 0; cb < 4; ++cb)
            #pragma unroll
            for (int r = 0; r < 4; ++r)
                Ob[(size_t)(cb * 16 + quad * 4 + r) * NPOS + i0 + rs * 16 + col] =
                    (unsigned short)f2bs(oacc[rs][cb][r]);
}

// ---------------------------------------------------------------------------
// Kernel 3: out = gamma/lsum * sum_jc Opart + x  (R8-verified body)
// ---------------------------------------------------------------------------
__global__ __launch_bounds__(256) void combine_kernel(
    const unsigned short* __restrict__ Opart, const float* __restrict__ lacc,
    const float* __restrict__ x, const float* __restrict__ gamma,
    float* __restrict__ out)
{
    int b  = blockIdx.x >> 7;
    int n0 = (blockIdx.x & 127) << 5;
    __shared__ float linv[32];
    int t = threadIdx.x;
    if (t < 32) {
        float s = 0.f;
        #pragma unroll
        for (int jc = 0; jc < JSPLIT; ++jc)
            s += lacc[(size_t)(jc * BATCH + b) * NPOS + n0 + t];
        linv[t] = gamma[0] / s;
    }
    __syncthreads();

    int c = t >> 2, ns = (t & 3) * 8;
    float acc[8];
    #pragma unroll
    for (int k = 0; k < 8; ++k) acc[k] = 0.f;
    #pragma unroll
    for (int jc = 0; jc < JSPLIT; ++jc) {
        const unsigned short* Ob = Opart + ((size_t)(jc * BATCH + b) * CDIM + c) * NPOS + n0 + ns;
        u32x4 w = *(const u32x4*)Ob;
        #pragma unroll
        for (int j = 0; j < 4; ++j) {
            acc[2 * j]     += bffloat(w[j] << 16);
            acc[2 * j + 1] += bffloat(w[j] & 0xffff0000u);
        }
    }
    const float* xb = x + ((size_t)b * CDIM + c) * NPOS + n0 + ns;
    float* ob = out + ((size_t)b * CDIM + c) * NPOS + n0 + ns;
    #pragma unroll
    for (int k = 0; k < 2; ++k) {
        f32x4 x4 = *(const f32x4*)(xb + k * 4);
        f32x4 r;
        #pragma unroll
        for (int j = 0; j < 4; ++j)
            r[j] = fmaf(acc[k * 4 + j], linv[ns + k * 4 + j], x4[j]);
        *(f32x4*)(ob + k * 4) = r;
    }
}

extern "C" void kernel_launch(void* const* d_in, const int* in_sizes, int n_in,
                              void* d_out, int out_size, void* d_ws, size_t ws_size,
                              hipStream_t stream) {
    const float* x     = (const float*)d_in[0];
    const float* q_dw  = (const float*)d_in[1];
    const float* q_pw  = (const float*)d_in[2];
    const float* k_dw  = (const float*)d_in[3];
    const float* k_pw  = (const float*)d_in[4];
    const float* v_dw  = (const float*)d_in[5];
    const float* v_pw  = (const float*)d_in[6];
    const float* gamma = (const float*)d_in[7];
    float* out = (float*)d_out;

    // ws: qT 1M | kT 1M | vM 1M | Opart 16.8M | lacc 512K
    char* ws = (char*)d_ws;
    short* qT             = (short*)(ws);
    short* kT             = (short*)(ws + (1u << 20));
    short* vM             = (short*)(ws + (2u << 20));
    unsigned short* Opart = (unsigned short*)(ws + (3u << 20));
    float* lacc           = (float*)(ws + (3u << 20) +
                                     (size_t)JSPLIT * BATCH * CDIM * NPOS * 2);

    qkv_kernel<<<3 * BATCH * 256, 64, 0, stream>>>(
        x, q_dw, q_pw, k_dw, k_pw, v_dw, v_pw, qT, kT, vM);
    attn_kernel<<<BATCH * 32 * JSPLIT, 256, 0, stream>>>(qT, kT, vM, Opart, lacc);
    combine_kernel<<<BATCH * 128, 256, 0, stream>>>(Opart, lacc, x, gamma, out);
}